// Round 10
// baseline (378.805 us; speedup 1.0000x reference)
//
#include <hip/hip_runtime.h>
#include <cstdint>

typedef unsigned short u16;
typedef __attribute__((ext_vector_type(8))) __bf16 bf16x8;
typedef __attribute__((ext_vector_type(4))) float f32x4;

#define S_LEN 2048

__device__ __forceinline__ u16 f2bf(float f) {  // HW RNE cvt (1 VALU op)
  __bf16 h = (__bf16)f;
  return __builtin_bit_cast(u16, h);
}
__device__ __forceinline__ uint32_t pk2(float a, float b) {  // pairs -> v_cvt_pk_bf16_f32
  return (uint32_t)f2bf(a) | ((uint32_t)f2bf(b) << 16);
}
__device__ __forceinline__ float bf2f(u16 h) {
  return __builtin_bit_cast(float, (uint32_t)h << 16);
}
__device__ __forceinline__ bf16x8 ldfrag(const u16* p) {
  return __builtin_bit_cast(bf16x8, *(const uint4*)p);
}
__device__ __forceinline__ f32x4 mfma16(bf16x8 a, bf16x8 b, f32x4 c) {
  return __builtin_amdgcn_mfma_f32_16x16x32_bf16(a, b, c, 0, 0, 0);
}
// async 16B global -> LDS (dest = wave-uniform base + lane*16)
__device__ __forceinline__ void glds16(const u16* g, u16* l) {
  __builtin_amdgcn_global_load_lds((const __attribute__((address_space(1))) void*)g,
                                   (__attribute__((address_space(3))) void*)l, 16, 0, 0);
}

// ------------- fused prep: x cvt + 4x weight transpose-convert + rope table -------------
__device__ __forceinline__ void cvtT_body(const float* __restrict__ W, u16* __restrict__ Wt,
                                          int K, int N, int n0, int k0, int tid,
                                          float (*t)[33]) {
  int tx = tid & 31, ty = tid >> 5;
#pragma unroll
  for (int j = 0; j < 4; ++j)
    t[ty + 8 * j][tx] = W[(long)(k0 + ty + 8 * j) * N + n0 + tx];
  __syncthreads();
#pragma unroll
  for (int j = 0; j < 4; ++j)
    Wt[(long)(n0 + ty + 8 * j) * K + k0 + tx] = f2bf(t[tx][ty + 8 * j]);
}

__global__ __launch_bounds__(256) void prep_kernel(const float* __restrict__ x,
                                                   const float* __restrict__ Wq,
                                                   const float* __restrict__ Wk,
                                                   const float* __restrict__ Wv,
                                                   const float* __restrict__ Wo,
                                                   u16* __restrict__ xb,
                                                   u16* __restrict__ WqkvT,
                                                   u16* __restrict__ WoT,
                                                   float2* __restrict__ ctab) {
  __shared__ float t[32][33];
  int blk = blockIdx.x, tid = threadIdx.x;
  if (blk < 8192) {  // x fp32 -> bf16, vectorized
    int i = blk * 256 + tid;
    float4 v = ((const float4*)x)[i];
    uint2 o;
    o.x = pk2(v.x, v.y);
    o.y = pk2(v.z, v.w);
    ((uint2*)xb)[i] = o;
  } else if (blk < 12288) {  // Wq^T
    int b2 = blk - 8192;
    cvtT_body(Wq, WqkvT, 2048, 2048, (b2 & 63) * 32, (b2 >> 6) * 32, tid, t);
  } else if (blk < 13312) {  // Wk^T
    int b2 = blk - 12288;
    cvtT_body(Wk, WqkvT + 4194304, 2048, 512, (b2 & 15) * 32, (b2 >> 4) * 32, tid, t);
  } else if (blk < 14336) {  // Wv^T
    int b2 = blk - 13312;
    cvtT_body(Wv, WqkvT + 5242880, 2048, 512, (b2 & 15) * 32, (b2 >> 4) * 32, tid, t);
  } else if (blk < 18432) {  // Wo^T
    int b2 = blk - 14336;
    cvtT_body(Wo, WoT, 2048, 2048, (b2 & 63) * 32, (b2 >> 6) * 32, tid, t);
  } else {  // rope table: ctab[s*32+i] = {cos,sin}(s * theta^(-i/32))
    int idx = (blk - 18432) * 256 + tid;
    int i = idx & 31, s = idx >> 5;
    float freq = exp2f(-(float)i * (13.287712379549449f / 32.0f));
    float sn, cs;
    sincosf((float)s * freq, &sn, &cs);
    ctab[idx] = make_float2(cs, sn);
  }
}

// ------------- GEMM: C = A[M][K](bf16) * Bt[N][K]^T(bf16) -------------
// 128x128 tile, 4 waves (2x2), BK=32. 3-buffer LDS, depth-2 async pipeline:
// per K-step {stage(t+2) -> compute buf -> vmcnt(4) -> s_barrier}.
// MODE: 0 = fp32 out row-major; 3 = fused QKV epilogue.
template <int MODE>
__global__ __launch_bounds__(256) void gemm_bt(const u16* __restrict__ A,
                                               const u16* __restrict__ Bt,
                                               void* __restrict__ C, int K, int ldc,
                                               u16* __restrict__ Kc_out,
                                               u16* __restrict__ Vt_out) {
  __shared__ __align__(16) u16 As[3][4096];
  __shared__ __align__(16) u16 Bs[3][4096];
  int tid = threadIdx.x;
  int lane = tid & 63, w = tid >> 6;
  int wr = (w >> 1) * 64, wc = (w & 1) * 64;
  int l15 = lane & 15, l4 = lane >> 4;
  int rowbase = blockIdx.x * 128, colbase = blockIdx.y * 128;
  f32x4 acc[4][4] = {};
  int r0 = tid >> 2, kc0 = (tid & 3) * 8;
  const u16* Ap0 = A + (long)(rowbase + r0) * K + kc0;
  const u16* Ap1 = A + (long)(rowbase + 64 + r0) * K + kc0;
  const u16* Bp0 = Bt + (long)(colbase + r0) * K + kc0;
  const u16* Bp1 = Bt + (long)(colbase + 64 + r0) * K + kc0;
  int wb = w * 512;  // wave-uniform LDS base (64 lanes x 16B = 1KB per wave)
  auto stage = [&](int t, int buf) {
    int ko = t * 32;
    glds16(Ap0 + ko, &As[buf][wb]);
    glds16(Ap1 + ko, &As[buf][2048 + wb]);
    glds16(Bp0 + ko, &Bs[buf][wb]);
    glds16(Bp1 + ko, &Bs[buf][2048 + wb]);
  };
  int nk = K >> 5;  // 64
  stage(0, 0);
  stage(1, 1);
  asm volatile("s_waitcnt vmcnt(4)" ::: "memory");
  __builtin_amdgcn_s_barrier();
  int cur = 0, nxt2 = 2;
  for (int t = 0; t < nk; ++t) {
    if (t + 2 < nk) stage(t + 2, nxt2);
    bf16x8 af[4], bv[4];
#pragma unroll
    for (int m = 0; m < 4; ++m) af[m] = ldfrag(&As[cur][(wr + m * 16 + l15) * 32 + l4 * 8]);
#pragma unroll
    for (int n = 0; n < 4; ++n) bv[n] = ldfrag(&Bs[cur][(wc + n * 16 + l15) * 32 + l4 * 8]);
#pragma unroll
    for (int m = 0; m < 4; ++m)
#pragma unroll
      for (int n = 0; n < 4; ++n) acc[m][n] = mfma16(af[m], bv[n], acc[m][n]);
    if (t + 1 < nk) {
      if (t + 2 < nk)
        asm volatile("s_waitcnt vmcnt(4)" ::: "memory");
      else
        asm volatile("s_waitcnt vmcnt(0)" ::: "memory");
      __builtin_amdgcn_s_barrier();
    }
    cur = cur == 2 ? 0 : cur + 1;
    nxt2 = nxt2 == 2 ? 0 : nxt2 + 1;
  }
  if (MODE == 0) {
#pragma unroll
    for (int m = 0; m < 4; ++m)
#pragma unroll
      for (int n = 0; n < 4; ++n)
#pragma unroll
        for (int r = 0; r < 4; ++r) {
          int row = rowbase + wr + m * 16 + l4 * 4 + r;
          int col = colbase + wc + n * 16 + l15;
          ((float*)C)[(long)row * ldc + col] = acc[m][n][r];
        }
  } else {  // MODE 3: fused QKV epilogue, block-uniform region select
    if (colbase < 2048) {  // Q rows (bf16, ld 2048)
#pragma unroll
      for (int m = 0; m < 4; ++m)
#pragma unroll
        for (int n = 0; n < 4; ++n)
#pragma unroll
          for (int r = 0; r < 4; ++r) {
            int row = rowbase + wr + m * 16 + l4 * 4 + r;
            int col = colbase + wc + n * 16 + l15;
            ((u16*)C)[(long)row * 2048 + col] = f2bf(acc[m][n][r]);
          }
    } else if (colbase < 2560) {  // K rows (bf16, ld 512)
#pragma unroll
      for (int m = 0; m < 4; ++m)
#pragma unroll
        for (int n = 0; n < 4; ++n)
#pragma unroll
          for (int r = 0; r < 4; ++r) {
            int row = rowbase + wr + m * 16 + l4 * 4 + r;
            int col = colbase + wc + n * 16 + l15 - 2048;
            Kc_out[(long)row * 512 + col] = f2bf(acc[m][n][r]);
          }
    } else {  // V -> Vt[b][kvh][d][s] transposed, 8B stores
#pragma unroll
      for (int m = 0; m < 4; ++m)
#pragma unroll
        for (int n = 0; n < 4; ++n) {
          int row = rowbase + wr + m * 16 + l4 * 4;  // = b*2048 + s, s%4==0
          int col = colbase + wc + n * 16 + l15 - 2560;  // = kvh*64 + d
          int b_ = row >> 11, s_ = row & 2047;
          int kvh_ = col >> 6, d_ = col & 63;
          uint2 o2;
          o2.x = pk2(acc[m][n][0], acc[m][n][1]);
          o2.y = pk2(acc[m][n][2], acc[m][n][3]);
          *(uint2*)&Vt_out[((long)((b_ * 8 + kvh_) * 64 + d_)) * 2048 + s_] = o2;
        }
    }
  }
}

// ------------- fused K/V repack to fragment-major (K: + RoPE) -------------
__global__ __launch_bounds__(256) void kvpack_kernel(const u16* __restrict__ Ks,
                                                     const float2* __restrict__ ctab,
                                                     u16* __restrict__ Kp,
                                                     const u16* __restrict__ Vt,
                                                     u16* __restrict__ Vp) {
  int blk = blockIdx.x;
  if (blk < 1024) {  // K repack + RoPE
    int idx = blk * 256 + threadIdx.x;  // 262144 chunks
    int lane = idx & 63, half = (idx >> 6) & 1, n = (idx >> 7) & 3;
    int t = (idx >> 9) & 31, kvh = (idx >> 14) & 7, b = idx >> 17;
    int l15 = lane & 15, l4 = lane >> 4;
    int s = t * 64 + n * 16 + l15;
    int d0 = half * 32 + l4 * 8;
    const u16* src = Ks + ((long)(b * 2048 + s)) * 512 + kvh * 64 + d0;
    uint4 v = *(const uint4*)src;
    const float2* ct = ctab + s * 32 + (d0 >> 1);
    uint32_t o[4];
#pragma unroll
    for (int jj = 0; jj < 4; ++jj) {
      uint32_t vw = ((const uint32_t*)&v)[jj];
      float2 cs = ct[jj];
      float e = bf2f((u16)vw), od = bf2f((u16)(vw >> 16));
      o[jj] = pk2(e * cs.x - od * cs.y, e * cs.y + od * cs.x);
    }
    *(uint4*)(Kp + (long)idx * 8) = *(uint4*)o;
  } else {  // V repack
    int idx = (blk - 1024) * 256 + threadIdx.x;
    int lane = idx & 63, half = (idx >> 6) & 1, f = (idx >> 7) & 3;
    int t = (idx >> 9) & 31, kvh = (idx >> 14) & 7, b = idx >> 17;
    int l15 = lane & 15, l4 = lane >> 4;
    const u16* src = Vt + ((long)((b * 8 + kvh) * 64 + f * 16 + l15)) * 2048 +
                     t * 64 + half * 32 + l4 * 8;
    *(uint4*)(Vp + (long)idx * 8) = *(const uint4*)src;
  }
}

// ---------------- Flash attention v6 (causal, GQA 4:1, fragment-major K/V) ----------------
// Uniform waves: block i owns chunks {4i..4i+3} -> all 4 waves have nt = i+1
// (imbalance only across blocks; 8 blocks/CU backfill absorbs it).
// Softmax in log2 domain (log2e folded into Q scale), HW bf16 cvt packing,
// setprio around MFMA clusters.
__global__ __launch_bounds__(256, 8) void attn_kernel(const u16* __restrict__ Q,
                                                      const u16* __restrict__ Kp,
                                                      const u16* __restrict__ Vp,
                                                      const float2* __restrict__ ctab,
                                                      u16* __restrict__ O) {
  int bid = blockIdx.x;
  int i = bid & 31, h = (bid >> 5) & 31, b = bid >> 10;
  int kvh = h >> 2;
  int tid = threadIdx.x, lane = tid & 63, w = tid >> 6;
  int l15 = lane & 15, l4 = lane >> 4;
  int c = 4 * i + w;  // chunk of 16 q-rows; nt identical across the block's waves
  int qb = c * 16;
  int nt = i + 1;  // kv tiles of 64
  __shared__ u16 Ps[4][16][72];  // per-wave P tile [q][k], stride 72
  u16(*myPs)[72] = Ps[w];
  const u16* Qh = Q + (long)b * S_LEN * 2048 + h * 64;
  const u16* Kh = Kp + (long)(b * 8 + kvh) * 131072;  // 32t x 4n x 2half x 64lane x 8
  const u16* Vh = Vp + (long)(b * 8 + kvh) * 131072;
  u16* Oh = O + (long)b * S_LEN * 2048 + h * 64;
  // ---- load Q row (q = qb+l15), RoPE in-register; scale folds 1/8 * log2(e)
  int s = qb + l15;
  const u16* qp = Qh + (long)s * 2048;
  uint4 r0 = *(const uint4*)(qp + l4 * 8);       // pairs i = l4*4 + jj
  uint4 r1 = *(const uint4*)(qp + 32 + l4 * 8);  // pairs i = 16 + l4*4 + jj
  const float2* ct = ctab + (long)s * 32 + l4 * 4;
  const float QSC = 0.18033688011112042f;  // 0.125 * log2(e)
  uint32_t q0w[4], q1w[4];
#pragma unroll
  for (int jj = 0; jj < 4; ++jj) {
    float2 cs0 = ct[jj], cs1 = ct[16 + jj];
    uint32_t v0 = ((const uint32_t*)&r0)[jj], v1 = ((const uint32_t*)&r1)[jj];
    float e0 = bf2f((u16)v0), o0 = bf2f((u16)(v0 >> 16));
    float e1 = bf2f((u16)v1), o1 = bf2f((u16)(v1 >> 16));
    q0w[jj] = pk2((e0 * cs0.x - o0 * cs0.y) * QSC, (e0 * cs0.y + o0 * cs0.x) * QSC);
    q1w[jj] = pk2((e1 * cs1.x - o1 * cs1.y) * QSC, (e1 * cs1.y + o1 * cs1.x) * QSC);
  }
  bf16x8 qf0 = __builtin_bit_cast(bf16x8, *(uint4*)q0w);
  bf16x8 qf1 = __builtin_bit_cast(bf16x8, *(uint4*)q1w);
  float m_r = -INFINITY, l_r = 0.f;
  f32x4 oaccT[4] = {};
  int lane8 = lane * 8;
  for (int t = 0; t < nt; ++t) {
    const u16* kt = Kh + t * 4096;  // 4n x 2half x 512
    f32x4 sacc[4] = {};
    __builtin_amdgcn_s_setprio(1);
#pragma unroll
    for (int n = 0; n < 4; ++n) {  // S^T[64k][16q] in log2 units
      sacc[n] = mfma16(ldfrag(kt + n * 1024 + lane8), qf0, sacc[n]);
      sacc[n] = mfma16(ldfrag(kt + n * 1024 + 512 + lane8), qf1, sacc[n]);
    }
    __builtin_amdgcn_s_setprio(0);
    if (t == nt - 1) {  // causal mask: k = t*64+n*16+l4*4+r, q = qb+l15
      int kb = t * 64;
#pragma unroll
      for (int n = 0; n < 4; ++n) {
        int kc_ = kb + n * 16 + l4 * 4;
#pragma unroll
        for (int r = 0; r < 4; ++r)
          if (kc_ + r > qb + l15) sacc[n][r] = -1e30f;
      }
    }
    float mx = fmaxf(fmaxf(fmaxf(sacc[0][0], sacc[0][1]), fmaxf(sacc[0][2], sacc[0][3])),
                     fmaxf(fmaxf(sacc[1][0], sacc[1][1]), fmaxf(sacc[1][2], sacc[1][3])));
    mx = fmaxf(mx, fmaxf(fmaxf(fmaxf(sacc[2][0], sacc[2][1]), fmaxf(sacc[2][2], sacc[2][3])),
                         fmaxf(fmaxf(sacc[3][0], sacc[3][1]), fmaxf(sacc[3][2], sacc[3][3]))));
    mx = fmaxf(mx, __shfl_xor(mx, 16));
    mx = fmaxf(mx, __shfl_xor(mx, 32));
    float mn = fmaxf(m_r, mx);
    float fac = exp2f(m_r - mn);
    m_r = mn;
    float rs = 0.f;
#pragma unroll
    for (int n = 0; n < 4; ++n) {
      float p0 = exp2f(sacc[n][0] - mn);
      float p1 = exp2f(sacc[n][1] - mn);
      float p2 = exp2f(sacc[n][2] - mn);
      float p3 = exp2f(sacc[n][3] - mn);
      rs += (p0 + p1) + (p2 + p3);
      uint2 o2;
      o2.x = pk2(p0, p1);
      o2.y = pk2(p2, p3);
      *(uint2*)&myPs[l15][n * 16 + l4 * 4] = o2;
    }
    rs += __shfl_xor(rs, 16);
    rs += __shfl_xor(rs, 32);
    l_r = l_r * fac + rs;
#pragma unroll
    for (int f = 0; f < 4; ++f) {  // O^T rescale: per-lane fac (q = l15)
      oaccT[f][0] *= fac; oaccT[f][1] *= fac;
      oaccT[f][2] *= fac; oaccT[f][3] *= fac;
    }
    bf16x8 pa0 = ldfrag(&myPs[l15][l4 * 8]);
    bf16x8 pa1 = ldfrag(&myPs[l15][32 + l4 * 8]);
    const u16* vt = Vh + t * 4096;  // 4f x 2half x 512
    __builtin_amdgcn_s_setprio(1);
#pragma unroll
    for (int f = 0; f < 4; ++f) {  // O^T[64d][16q] += V^T * P^T; contiguous frags
      oaccT[f] = mfma16(ldfrag(vt + f * 1024 + lane8), pa0, oaccT[f]);
      oaccT[f] = mfma16(ldfrag(vt + f * 1024 + 512 + lane8), pa1, oaccT[f]);
    }
    __builtin_amdgcn_s_setprio(0);
  }
  float linv = 1.f / l_r;  // per-lane (q = l15)
#pragma unroll
  for (int f = 0; f < 4; ++f) {
    uint2 o2;
    o2.x = pk2(oaccT[f][0] * linv, oaccT[f][1] * linv);
    o2.y = pk2(oaccT[f][2] * linv, oaccT[f][3] * linv);
    *(uint2*)&Oh[(long)(qb + l15) * 2048 + f * 16 + l4 * 4] = o2;  // 8B store
  }
}

// ---------------- launch ----------------
extern "C" void kernel_launch(void* const* d_in, const int* in_sizes, int n_in,
                              void* d_out, int out_size, void* d_ws, size_t ws_size,
                              hipStream_t stream) {
  const float* x = (const float*)d_in[0];
  const float* Wq = (const float*)d_in[1];
  const float* Wk = (const float*)d_in[2];
  const float* Wv = (const float*)d_in[3];
  const float* Wo = (const float*)d_in[4];
  float* out = (float*)d_out;
  char* ws = (char*)d_ws;
  // workspace layout (bytes)
  u16* xb = (u16*)(ws + 0);             // 4096x2048 bf16 (16 MiB) [dead after gemmQKV]
  u16* WqkvT = (u16*)(ws + 16777216);   // 3072x2048      (12 MiB) rows: Q|K|V
  u16* WoT = (u16*)(ws + 29360128);     // 2048x2048      (8 MiB)
  u16* Qs = (u16*)(ws + 37748736);      // 4096x2048      (16 MiB)
  u16* Ks = (u16*)(ws + 54525952);      // 4096x512       (4 MiB)
  u16* Vt = (u16*)(ws + 58720256);      // [2][8][64][2048] (4 MiB)
  u16* Os = (u16*)(ws + 62914560);      // 4096x2048      (16 MiB) [ends 79691776]
  u16* Kp = (u16*)(ws + 0);             // packed K (4 MiB) -- aliases dead xb
  u16* Vp = (u16*)(ws + 4194304);       // packed V (4 MiB) -- aliases dead xb
  float2* ctab = (float2*)(ws + 79691776);  // 2048x32 cos/sin (512 KiB)

  prep_kernel<<<18688, 256, 0, stream>>>(x, Wq, Wk, Wv, Wo, xb, WqkvT, WoT, ctab);
  gemm_bt<3><<<dim3(32, 24), 256, 0, stream>>>(xb, WqkvT, Qs, 2048, 2048, Ks, Vt);
  kvpack_kernel<<<2048, 256, 0, stream>>>(Ks, ctab, Kp, Vt, Vp);
  attn_kernel<<<2048, 256, 0, stream>>>(Qs, Kp, Vp, ctab, Os);
  gemm_bt<0><<<dim3(32, 16), 256, 0, stream>>>(Os, WoT, out, 2048, 2048, nullptr, nullptr);
}